// Round 16
// baseline (144.879 us; speedup 1.0000x reference)
//
#include <hip/hip_runtime.h>
#include <stdint.h>

#define N_EMBD 1024
#define NHEAD  16
#define HDIM   64
#define BATCH  8
#define SEQ    1024
#define MROWS  (BATCH*SEQ)   // 8192

typedef __bf16 bf16x8 __attribute__((ext_vector_type(8)));
typedef float  f32x4  __attribute__((ext_vector_type(4)));

__device__ inline unsigned short f2bf(float f) {
  uint32_t u = __float_as_uint(f);
  u += 0x7FFFu + ((u >> 16) & 1u);   // RNE; inputs are finite
  return (unsigned short)(u >> 16);
}

__device__ inline f32x4 mfma_bf16(bf16x8 a, bf16x8 b, f32x4 c) {
  return __builtin_amdgcn_mfma_f32_16x16x32_bf16(a, b, c, 0, 0, 0);
}

__device__ inline void gload_lds16(const unsigned short* g, unsigned short* l) {
  __builtin_amdgcn_global_load_lds(
      (const __attribute__((address_space(1))) void*)g,
      (__attribute__((address_space(3))) void*)l,
      16, 0, 0);
}

#define DSB __builtin_amdgcn_sched_barrier(0)
#define BARRIER __builtin_amdgcn_s_barrier()
#define VMC(n) asm volatile("s_waitcnt vmcnt(" #n ")" ::: "memory")
#define LGKM0 asm volatile("s_waitcnt lgkmcnt(0)" ::: "memory"); DSB

// ---------------- merged prep: x cast (blocks 0..8191) + weight transposes ----------------
__global__ __launch_bounds__(256) void prep_kernel(
    const float* __restrict__ x, unsigned short* __restrict__ xb,
    const float* __restrict__ wa, unsigned short* __restrict__ oa,
    const float* __restrict__ wp, unsigned short* __restrict__ op) {
  int bid = blockIdx.x;
  int t = threadIdx.x;
  if (bid < 8192) {            // cast path: 8192 blocks x 1024 elems
    int i = (bid * 256 + t) * 4;
    float4 v = *(const float4*)(x + i);
    ushort4 o;
    o.x = f2bf(v.x); o.y = f2bf(v.y); o.z = f2bf(v.z); o.w = f2bf(v.w);
    *(ushort4*)(xb + i) = o;
    return;
  }
  // transpose path: 1024 blocks; idx -> (bx 0..63, ky 0..15)
  __shared__ unsigned short tile[64 * 72];
  int idx = bid - 8192;
  int bx = idx & 63;
  int ky = idx >> 6;
  const int K = 1024;
  const float* in; unsigned short* out; int N;
  if (bx < 48) { in = wa; out = oa; N = 3072; }
  else         { in = wp; out = op; N = 1024; bx -= 48; }
  int k0 = ky * 64, n0 = bx * 64;
  {
    int col = (t & 15) * 4;
#pragma unroll
    for (int it = 0; it < 4; ++it) {
      int row = (t >> 4) + it * 16;
      float4 v = *(const float4*)(in + (size_t)(k0 + row) * N + n0 + col);
      ushort4 o;
      o.x = f2bf(v.x); o.y = f2bf(v.y); o.z = f2bf(v.z); o.w = f2bf(v.w);
      *(ushort4*)&tile[row * 72 + col] = o;
    }
  }
  __syncthreads();
  {
    int kcol = (t & 7) * 8;
#pragma unroll
    for (int it = 0; it < 2; ++it) {
      int nrow = (t >> 3) + it * 32;
      alignas(16) unsigned short tmp[8];
#pragma unroll
      for (int j = 0; j < 8; ++j) tmp[j] = tile[(kcol + j) * 72 + nrow];
      *(uint4*)(out + (size_t)(n0 + nrow) * K + k0 + kcol) = *(const uint4*)tmp;
    }
  }
}

// ---------------- GEMM v11 (qkv): 256x128 tile, BK=64, single-buffer, 3 blocks/CU ------
// 4 waves (2M x 2N), per-wave 128x64 = acc[8][4]; reads/MFMA = 0.375.
// LDS 48KB single-buffer; plain 2-barrier loop (cross-block overlap at 3 blocks/CU).
// Zero-conflict XOR swizzle (R5-verified geometry). Cache-shaped grid: XCD owns 4
// m-bands (A 2MB resident); n walked in 3 chunks of 8 panels (B-slice 2MB).
__global__ __launch_bounds__(256, 3) void gemm_qkv(
    const unsigned short* __restrict__ A, const unsigned short* __restrict__ Bt,
    const float* __restrict__ bias,
    unsigned short* __restrict__ Qo, unsigned short* __restrict__ Ko,
    unsigned short* __restrict__ VTo) {
  __shared__ unsigned short Asl[256 * 64];   // 32KB
  __shared__ unsigned short Bsl[128 * 64];   // 16KB
  const int bid = blockIdx.x;
  const int xcd = bid & 7;
  const int local = bid >> 3;          // 0..95
  const int nchunk = local >> 5;       // 0..2
  const int rem = local & 31;
  const int m0 = (xcd * 4 + (rem >> 3)) * 256;
  const int n0 = (nchunk * 8 + (rem & 7)) * 128;
  const int tid = threadIdx.x;
  const int l = tid & 63, w = tid >> 6;
  const int wr = w >> 1, wc = w & 1;
  const int g = l >> 4, fr = l & 15;
  f32x4 acc[8][4];
#pragma unroll
  for (int i = 0; i < 8; ++i)
#pragma unroll
    for (int j = 0; j < 4; ++j)
#pragma unroll
      for (int r = 0; r < 4; ++r) acc[i][j][r] = 0.0f;
  const int rr = tid >> 3;
  const int cs = ((tid & 7) * 16) ^ ((rr & 7) << 4);
  const char* srcA[8];
  const char* srcB[4];
#pragma unroll
  for (int c = 0; c < 8; ++c)
    srcA[c] = (const char*)A + (size_t)(m0 + c * 32 + rr) * 2048 + cs;
#pragma unroll
  for (int c = 0; c < 4; ++c)
    srcB[c] = (const char*)Bt + (size_t)(n0 + c * 32 + rr) * 2048 + cs;
  const int ldso = tid * 8;  // shorts
  const int arow = (wr * 128 + fr) * 128;
  const int brow = (wc * 64 + fr) * 128;
  int colk[2];
  colk[0] = (g * 16) ^ ((fr & 7) << 4);
  colk[1] = (64 + g * 16) ^ ((fr & 7) << 4);
  for (int kt = 0; kt < 16; ++kt) {
    __syncthreads();   // all waves done reading previous tile
#pragma unroll
    for (int c = 0; c < 8; ++c)
      gload_lds16((const unsigned short*)(srcA[c] + kt * 128), &Asl[ldso + c * 2048]);
#pragma unroll
    for (int c = 0; c < 4; ++c)
      gload_lds16((const unsigned short*)(srcB[c] + kt * 128), &Bsl[ldso + c * 2048]);
    __syncthreads();   // drains vmcnt: tile visible
#pragma unroll
    for (int ks = 0; ks < 2; ++ks) {
      bf16x8 bv[4], av[4];
#pragma unroll
      for (int n = 0; n < 4; ++n)
        bv[n] = *(const bf16x8*)((const char*)Bsl + brow + n * 16 * 128 + colk[ks]);
#pragma unroll
      for (int m = 0; m < 4; ++m)
        av[m] = *(const bf16x8*)((const char*)Asl + arow + m * 16 * 128 + colk[ks]);
#pragma unroll
      for (int n = 0; n < 4; ++n)
#pragma unroll
        for (int m = 0; m < 4; ++m)
          acc[m][n] = mfma_bf16(av[m], bv[n], acc[m][n]);
#pragma unroll
      for (int m = 0; m < 4; ++m)
        av[m] = *(const bf16x8*)((const char*)Asl + arow + (m + 4) * 16 * 128 + colk[ks]);
#pragma unroll
      for (int n = 0; n < 4; ++n)
#pragma unroll
        for (int m = 0; m < 4; ++m)
          acc[m + 4][n] = mfma_bf16(av[m], bv[n], acc[m + 4][n]);
    }
  }
#pragma unroll
  for (int i = 0; i < 8; ++i) {
    int mb = m0 + wr * 128 + i * 16 + 4 * g;
    int bidx = mb >> 10;
    int t = mb & 1023;
#pragma unroll
    for (int j = 0; j < 4; ++j) {
      int n = n0 + wc * 64 + j * 16 + fr;
      float bv2 = bias[n];
      int part = n >> 10;
      int nn2 = n & 1023;
      int h = nn2 >> 6, d = nn2 & 63;
      if (part == 2) {
        alignas(8) unsigned short pk[4];
#pragma unroll
        for (int r = 0; r < 4; ++r) pk[r] = f2bf(acc[i][j][r] + bv2);
        *(ushort4*)&VTo[((size_t)(bidx * NHEAD + h) * HDIM + d) * SEQ + t] =
            *(const ushort4*)pk;
      } else {
        unsigned short* dst = (part == 0) ? Qo : Ko;
        // fold 1/sqrt(hd) AND log2(e) into Q so attn uses exp2 directly
        float scl = (part == 0) ? 0.18033688f : 1.0f;
        size_t base = ((size_t)(bidx * NHEAD + h) * SEQ + t) * HDIM + d;
#pragma unroll
        for (int r = 0; r < 4; ++r)
          dst[base + (size_t)r * HDIM] = f2bf((acc[i][j][r] + bv2) * scl);
      }
    }
  }
}

// ---------------- proj GEMM (unchanged R15 structure: dbuf + counted vmcnt) ----------------
__global__ __launch_bounds__(256) void gemm_proj(
    const unsigned short* __restrict__ A, const unsigned short* __restrict__ Bt,
    const float* __restrict__ bias, float* __restrict__ Out) {
  __shared__ unsigned short Asl[2][8192];
  __shared__ unsigned short Bsl[2][8192];
  const int bid = blockIdx.x;
  const int xcd = bid & 7;
  const int local = bid >> 3;          // 0..63
  const int m0 = (xcd * 8 + (local >> 3)) * 128;
  const int n0 = (local & 7) * 128;
  const int tid = threadIdx.x;
  const int l = tid & 63, w = tid >> 6;
  const int wr = w >> 1, wc = w & 1;
  const int g = l >> 4, fr = l & 15;
  f32x4 acc[4][4];
#pragma unroll
  for (int i = 0; i < 4; ++i)
#pragma unroll
    for (int j = 0; j < 4; ++j)
#pragma unroll
      for (int r = 0; r < 4; ++r) acc[i][j][r] = 0.0f;
  const int rr = tid >> 3;
  const int cs = ((tid & 7) * 16) ^ ((rr & 7) << 4);
  const char* srcA[4]; const char* srcB[4];
#pragma unroll
  for (int c = 0; c < 4; ++c) {
    srcA[c] = (const char*)A + (size_t)(m0 + c * 32 + rr) * 2048 + cs;
    srcB[c] = (const char*)Bt + (size_t)(n0 + c * 32 + rr) * 2048 + cs;
  }
  const int ldso = tid * 8;
  const int arow = (wr * 64 + fr) * 128;
  const int brow = (wc * 64 + fr) * 128;
  int colk[2];
  colk[0] = (g * 16) ^ ((fr & 7) << 4);
  colk[1] = (64 + g * 16) ^ ((fr & 7) << 4);
#pragma unroll
  for (int c = 0; c < 4; ++c)
    gload_lds16((const unsigned short*)(srcA[c]), &Asl[0][ldso + c * 2048]);
#pragma unroll
  for (int c = 0; c < 4; ++c)
    gload_lds16((const unsigned short*)(srcB[c]), &Bsl[0][ldso + c * 2048]);
#pragma unroll
  for (int c = 0; c < 4; ++c)
    gload_lds16((const unsigned short*)(srcA[c] + 128), &Asl[1][ldso + c * 2048]);
#pragma unroll
  for (int c = 0; c < 4; ++c)
    gload_lds16((const unsigned short*)(srcB[c] + 128), &Bsl[1][ldso + c * 2048]);
  for (int kt = 0; kt < 16; ++kt) {
    const int cur = kt & 1;
    if (kt < 15) { VMC(8); } else { VMC(0); }
    DSB; BARRIER; DSB;
#pragma unroll
    for (int ks = 0; ks < 2; ++ks) {
      bf16x8 av[4], bv[4];
#pragma unroll
      for (int m = 0; m < 4; ++m)
        av[m] = *(const bf16x8*)((const char*)&Asl[cur][0] + arow + m * 16 * 128 + colk[ks]);
#pragma unroll
      for (int n = 0; n < 4; ++n)
        bv[n] = *(const bf16x8*)((const char*)&Bsl[cur][0] + brow + n * 16 * 128 + colk[ks]);
#pragma unroll
      for (int n = 0; n < 4; ++n)
#pragma unroll
        for (int m = 0; m < 4; ++m)
          acc[m][n] = mfma_bf16(av[m], bv[n], acc[m][n]);
    }
    LGKM0; BARRIER; DSB;
    if (kt < 14) {
      const int ko = (kt + 2) * 128;
#pragma unroll
      for (int c = 0; c < 4; ++c)
        gload_lds16((const unsigned short*)(srcA[c] + ko), &Asl[cur][ldso + c * 2048]);
#pragma unroll
      for (int c = 0; c < 4; ++c)
        gload_lds16((const unsigned short*)(srcB[c] + ko), &Bsl[cur][ldso + c * 2048]);
    }
  }
#pragma unroll
  for (int i = 0; i < 4; ++i) {
    int mb = m0 + wr * 64 + i * 16 + 4 * g;
#pragma unroll
    for (int j = 0; j < 4; ++j) {
      int n = n0 + wc * 64 + j * 16 + fr;
      float bv2 = bias[n];
#pragma unroll
      for (int r = 0; r < 4; ++r)
        Out[(size_t)(mb + r) * N_EMBD + n] = acc[i][j][r] + bv2;
    }
  }
}

// ---------------- flash attention v2 (R12 structure; exp2 instead of exp) ----------------
__global__ __launch_bounds__(256) void attn_kernel(
    const unsigned short* __restrict__ Q, const unsigned short* __restrict__ Kv,
    const unsigned short* __restrict__ VT, unsigned short* __restrict__ Y) {
  __shared__ unsigned short Kt[2][4096];
  __shared__ unsigned short Vt[2][4096];
  __shared__ unsigned short p_lds[4 * 32 * 72];
  __shared__ float smx[4][32];
  int tid = threadIdx.x, l = tid & 63, w = tid >> 6;
  int bid = blockIdx.x;
  int swz = (bid & 7) * 64 + (bid >> 3);   // bijective (512 % 8 == 0)
  int bh = swz >> 2;
  int pairIdx = swz & 3;
  int b = bh >> 4, h = bh & 15;
  const unsigned short* Qb = Q + (size_t)bh * SEQ * HDIM;
  const char* Kc = (const char*)(Kv + (size_t)bh * SEQ * HDIM);
  const char* Vc = (const char*)(VT + (size_t)bh * HDIM * SEQ);
  unsigned short* pw = &p_lds[w * 32 * 72];
  const int g = l >> 4;
  const int fr = l & 15;

  const int P0 = tid * 16, P1 = tid * 16 + 4096;
  const int r0 = P0 >> 7, r1 = P1 >> 7;
  const int s0 = (P0 & 127) ^ ((r0 & 7) << 4);
  const int s1 = (P1 & 127) ^ ((r1 & 7) << 4);
  const char* Kg0 = Kc + r0 * 128 + s0;
  const char* Kg1 = Kc + r1 * 128 + s1;
  const char* Vg0 = Vc + (size_t)r0 * 2048 + s0;
  const char* Vg1 = Vc + (size_t)r1 * 2048 + s1;

  const int bc = (16 * g) ^ ((l & 7) << 4);

  for (int part = 0; part < 2; ++part) {
    const int qt = (part == 0) ? pairIdx : 7 - pairIdx;   // light first (L2 prefix)
    const int q0 = qt * 128;
    const int wq = q0 + w * 32;

    bf16x8 aq[2][2];
#pragma unroll
    for (int i = 0; i < 2; ++i)
#pragma unroll
      for (int ik = 0; ik < 2; ++ik)
        aq[i][ik] = *(const bf16x8*)&Qb[(size_t)(wq + i * 16 + fr) * HDIM + ik * 32 + 8 * g];

    float mrun[2], lpart[2];
    mrun[0] = mrun[1] = 0.0f;      // valid: rescale path handles any exceedance
    lpart[0] = lpart[1] = 0.0f;
    f32x4 acc_o[2][4];
#pragma unroll
    for (int i = 0; i < 2; ++i)
#pragma unroll
      for (int jd = 0; jd < 4; ++jd)
#pragma unroll
        for (int r = 0; r < 4; ++r) acc_o[i][jd][r] = 0.0f;

    const int n_it = (q0 + 128) >> 6;

    gload_lds16((const unsigned short*)(Kg0), &Kt[0][P0 >> 1]);
    gload_lds16((const unsigned short*)(Kg1), &Kt[0][P1 >> 1]);
    gload_lds16((const unsigned short*)(Vg0), &Vt[0][P0 >> 1]);
    gload_lds16((const unsigned short*)(Vg1), &Vt[0][P1 >> 1]);

    for (int it = 0; it < n_it; ++it) {
      const int kv0 = it << 6;
      const int cur = it & 1;
      if (it + 1 < n_it) {
        const int nx = kv0 + 64;
        gload_lds16((const unsigned short*)(Kg0 + nx * 128), &Kt[cur ^ 1][P0 >> 1]);
        gload_lds16((const unsigned short*)(Kg1 + nx * 128), &Kt[cur ^ 1][P1 >> 1]);
        gload_lds16((const unsigned short*)(Vg0 + nx * 2),   &Vt[cur ^ 1][P0 >> 1]);
        gload_lds16((const unsigned short*)(Vg1 + nx * 2),   &Vt[cur ^ 1][P1 >> 1]);
        VMC(4);
      } else {
        VMC(0);
      }
      DSB; BARRIER; DSB;

      const char* Kbuf = (const char*)Kt[cur];
      const char* Vbuf = (const char*)Vt[cur];

      f32x4 s2[2][4];
#pragma unroll
      for (int i = 0; i < 2; ++i)
#pragma unroll
        for (int j = 0; j < 4; ++j)
#pragma unroll
          for (int r = 0; r < 4; ++r) s2[i][j][r] = 0.0f;

      __builtin_amdgcn_s_setprio(1);
#pragma unroll
      for (int ik = 0; ik < 2; ++ik) {
#pragma unroll
        for (int j = 0; j < 4; ++j) {
          bf16x8 bk = *(const bf16x8*)(Kbuf + (j * 16 + fr) * 128 + (bc ^ (ik << 6)));
#pragma unroll
          for (int i = 0; i < 2; ++i) s2[i][j] = mfma_bf16(bk, aq[i][ik], s2[i][j]);
        }
      }
      __builtin_amdgcn_s_setprio(0);

      bool need_mask = (kv0 + 63) > wq;
      if (need_mask) {
#pragma unroll
        for (int i = 0; i < 2; ++i) {
          int q = wq + i * 16 + fr;
#pragma unroll
          for (int j = 0; j < 4; ++j)
#pragma unroll
            for (int r = 0; r < 4; ++r) {
              int kv = kv0 + j * 16 + 4 * g + r;
              if (kv > q) s2[i][j][r] = -3.0e38f;
            }
        }
      }

      float pmloc[2];
#pragma unroll
      for (int i = 0; i < 2; ++i) {
        float m01 = fmaxf(fmaxf(s2[i][0][0], s2[i][0][1]), fmaxf(s2[i][0][2], s2[i][0][3]));
        float m11 = fmaxf(fmaxf(s2[i][1][0], s2[i][1][1]), fmaxf(s2[i][1][2], s2[i][1][3]));
        float m21 = fmaxf(fmaxf(s2[i][2][0], s2[i][2][1]), fmaxf(s2[i][2][2], s2[i][2][3]));
        float m31 = fmaxf(fmaxf(s2[i][3][0], s2[i][3][1]), fmaxf(s2[i][3][2], s2[i][3][3]));
        pmloc[i] = fmaxf(fmaxf(m01, m11), fmaxf(m21, m31));
      }
      // base-2 domain: threshold 8*log2(e) keeps P <= e^8 as before
      bool ok = (pmloc[0] <= mrun[0] + 11.5409f) && (pmloc[1] <= mrun[1] + 11.5409f);
      if (!__all(ok)) {   // rare: full reduce + rescale
#pragma unroll
        for (int i = 0; i < 2; ++i) {
          float mm = pmloc[i];
          mm = fmaxf(mm, __shfl_xor(mm, 16, 64));
          mm = fmaxf(mm, __shfl_xor(mm, 32, 64));
          float mn = fmaxf(mrun[i], mm);
          float sc = exp2f(mrun[i] - mn);
          mrun[i] = mn;
          lpart[i] *= sc;
          if (g == 0) smx[w][i * 16 + fr] = sc;
        }
        asm volatile("s_waitcnt lgkmcnt(0)" ::: "memory");
#pragma unroll
        for (int i = 0; i < 2; ++i)
#pragma unroll
          for (int r = 0; r < 4; ++r) {
            float sc = smx[w][i * 16 + 4 * g + r];
#pragma unroll
            for (int jd = 0; jd < 4; ++jd) acc_o[i][jd][r] *= sc;
          }
      }

#pragma unroll
      for (int i = 0; i < 2; ++i) {
#pragma unroll
        for (int j = 0; j < 4; ++j) {
          float p0 = exp2f(s2[i][j][0] - mrun[i]);
          float p1 = exp2f(s2[i][j][1] - mrun[i]);
          float p2 = exp2f(s2[i][j][2] - mrun[i]);
          float p3 = exp2f(s2[i][j][3] - mrun[i]);
          lpart[i] += (p0 + p1) + (p2 + p3);
          uint2 pk2;
          asm("v_cvt_pk_bf16_f32 %0, %1, %2" : "=v"(pk2.x) : "v"(p0), "v"(p1));
          asm("v_cvt_pk_bf16_f32 %0, %1, %2" : "=v"(pk2.y) : "v"(p2), "v"(p3));
          *(uint2*)&pw[(i * 16 + fr) * 72 + j * 16 + 4 * g] = pk2;
        }
      }

      __builtin_amdgcn_s_setprio(1);
#pragma unroll
      for (int ik2 = 0; ik2 < 2; ++ik2) {
        bf16x8 ap[2];
#pragma unroll
        for (int i = 0; i < 2; ++i)
          ap[i] = *(const bf16x8*)&pw[(i * 16 + fr) * 72 + ik2 * 32 + 8 * g];
#pragma unroll
        for (int jd = 0; jd < 4; ++jd) {
          bf16x8 bv = *(const bf16x8*)(Vbuf + (jd * 16 + fr) * 128 + (bc ^ (ik2 << 6)));
#pragma unroll
          for (int i = 0; i < 2; ++i) acc_o[i][jd] = mfma_bf16(ap[i], bv, acc_o[i][jd]);
        }
      }
      __builtin_amdgcn_s_setprio(0);

      asm volatile("s_waitcnt lgkmcnt(0)" ::: "memory");
      DSB; BARRIER; DSB;
    }

#pragma unroll
    for (int i = 0; i < 2; ++i) {
      float t = lpart[i];
      t += __shfl_xor(t, 16, 64);
      t += __shfl_xor(t, 32, 64);
      if (g == 0) smx[w][i * 16 + fr] = t;
    }
    asm volatile("s_waitcnt lgkmcnt(0)" ::: "memory");
#pragma unroll
    for (int i = 0; i < 2; ++i)
#pragma unroll
      for (int r = 0; r < 4; ++r) {
        float inv = 1.0f / smx[w][i * 16 + 4 * g + r];
        int q = wq + i * 16 + 4 * g + r;
#pragma unroll
        for (int jd = 0; jd < 4; ++jd)
          Y[((size_t)b * SEQ + q) * N_EMBD + h * HDIM + jd * 16 + fr] =
              f2bf(acc_o[i][jd][r] * inv);
      }
  }
}

// ---------------- launcher ----------------
extern "C" void kernel_launch(void* const* d_in, const int* in_sizes, int n_in,
                              void* d_out, int out_size, void* d_ws, size_t ws_size,
                              hipStream_t stream) {
  (void)in_sizes; (void)n_in; (void)out_size; (void)ws_size;
  const float* x      = (const float*)d_in[0];
  const float* w_attn = (const float*)d_in[1];
  const float* b_attn = (const float*)d_in[2];
  const float* w_proj = (const float*)d_in[3];
  const float* b_proj = (const float*)d_in[4];
  float* out = (float*)d_out;

  char* ws = (char*)d_ws;
  size_t off = 0;
  auto carve = [&](size_t bytes) -> char* {
    char* p = ws + off;
    off += (bytes + 255) & ~(size_t)255;
    return p;
  };
  unsigned short* xb     = (unsigned short*)carve((size_t)MROWS * N_EMBD * 2);
  unsigned short* wTattn = (unsigned short*)carve((size_t)3 * N_EMBD * N_EMBD * 2);
  unsigned short* wTproj = (unsigned short*)carve((size_t)N_EMBD * N_EMBD * 2);
  unsigned short* Qb     = (unsigned short*)carve((size_t)MROWS * N_EMBD * 2);
  unsigned short* Kb     = (unsigned short*)carve((size_t)MROWS * N_EMBD * 2);
  unsigned short* VTb    = (unsigned short*)carve((size_t)MROWS * N_EMBD * 2);
  unsigned short* Yb     = (unsigned short*)carve((size_t)MROWS * N_EMBD * 2);
  carve(4096);

  prep_kernel<<<dim3(8192 + 1024), 256, 0, stream>>>(x, xb, w_attn, wTattn, w_proj, wTproj);
  gemm_qkv<<<dim3(768), 256, 0, stream>>>(xb, wTattn, b_attn, Qb, Kb, VTb);
  attn_kernel<<<dim3(512), 256, 0, stream>>>(Qb, Kb, VTb, Yb);
  gemm_proj<<<dim3(512), 256, 0, stream>>>(Yb, wTproj, b_proj, out);
}